// Round 3
// baseline (1194.318 us; speedup 1.0000x reference)
//
#include <hip/hip_runtime.h>

#define Bdim 2
#define Tdim 2048
#define Cdim 2048
#define Hn 16
#define Dh 128
#define NKB 16   // Cdim/128 k-blocks per row

typedef float f32x4 __attribute__((ext_vector_type(4)));
typedef short s16x8 __attribute__((ext_vector_type(8)));

// ---------- numerics helpers ----------

// fp32 -> float8_e5m2 (RNE, subnormals, inf past 61440) -> fp32. Matches ml_dtypes.
__device__ __forceinline__ float q8_e5m2(float x) {
    unsigned int u = __float_as_uint(x);
    unsigned int sign = u & 0x80000000u;
    float ax = __uint_as_float(u & 0x7fffffffu);
    float r;
    if (ax < 6.103515625e-05f) {              // subnormal range: grid 2^-16
        r = rintf(ax * 65536.0f) * (1.0f / 65536.0f);
    } else if (ax >= 61440.0f) {
        r = __uint_as_float(0x7f800000u);
    } else {
        unsigned int m = __float_as_uint(ax);
        unsigned int rem  = m & 0x001FFFFFu;
        unsigned int keep = m & 0xFFE00000u;
        unsigned int lsb  = (m >> 21) & 1u;
        if (rem > 0x00100000u || (rem == 0x00100000u && lsb)) keep += 0x00200000u;
        r = __uint_as_float(keep);
    }
    return __uint_as_float(__float_as_uint(r) | sign);
}

__device__ __forceinline__ unsigned short f2bf(float f) {
    unsigned int u = __float_as_uint(f);
    u += 0x7fffu + ((u >> 16) & 1u);
    return (unsigned short)(u >> 16);
}
__device__ __forceinline__ float bf2f(unsigned short h) {
    return __uint_as_float((unsigned int)h << 16);
}

// ---------- act quant: per-128 block. out = bf16(q8(x/s)) [EXACT] + scale ----------
__global__ __launch_bounds__(256) void act_quant_q8_k(const float* __restrict__ in,
                                                      unsigned short* __restrict__ q,
                                                      float* __restrict__ S, int n128) {
    int wid = (int)((blockIdx.x * 256u + threadIdx.x) >> 6);
    int lane = threadIdx.x & 63;
    if (wid >= n128) return;
    const float* p = in + (size_t)wid * 128;
    float a = p[lane], b = p[lane + 64];
    float m = fmaxf(fabsf(a), fabsf(b));
#pragma unroll
    for (int o = 32; o; o >>= 1) m = fmaxf(m, __shfl_xor(m, o));
    float s = fmaxf(m / 57344.0f, 1e-12f);
    unsigned short* qp = q + (size_t)wid * 128;
    qp[lane]      = f2bf(q8_e5m2(a / s));
    qp[lane + 64] = f2bf(q8_e5m2(b / s));
    if (lane == 0) S[wid] = s;
}

// ---------- weight quant: out = bf16(q8(w)) [EXACT, scale in GEMM epilogue] ----------
__global__ __launch_bounds__(256) void w_quant_k(const float* __restrict__ w,
                                                 unsigned short* __restrict__ out, int n) {
    int i = (blockIdx.x * 256 + threadIdx.x) * 4;
    if (i >= n) return;
    float4 t = *(const float4*)(w + i);
    out[i + 0] = f2bf(q8_e5m2(t.x));
    out[i + 1] = f2bf(q8_e5m2(t.y));
    out[i + 2] = f2bf(q8_e5m2(t.z));
    out[i + 3] = f2bf(q8_e5m2(t.w));
}

// ---------- GEMM: C[M,N] = (Aq * Sa_blockwise) @ Bq^T * Sb_col ----------
#define LDST 40

template<int OUTF32>
__global__ __launch_bounds__(256) void gemm_k(const unsigned short* __restrict__ Aq,
                                              const float* __restrict__ Sa,
                                              const unsigned short* __restrict__ Bq,
                                              const float* __restrict__ Sb,
                                              unsigned short* __restrict__ Oh,
                                              unsigned short* __restrict__ Ol,
                                              float* __restrict__ Of,
                                              int M, int N, int K) {
    __shared__ unsigned short As[128 * LDST];
    __shared__ unsigned short Bs[128 * LDST];
    int tid = threadIdx.x;
    int lane = tid & 63, wid = tid >> 6;
    int wr = wid >> 1, wc = wid & 1;
    int bm = blockIdx.y * 128, bn = blockIdx.x * 128;

    f32x4 acc[4][4], accp[4][4];
#pragma unroll
    for (int i = 0; i < 4; ++i)
#pragma unroll
        for (int j = 0; j < 4; ++j) {
            acc[i][j] = (f32x4){0.f, 0.f, 0.f, 0.f};
            accp[i][j] = (f32x4){0.f, 0.f, 0.f, 0.f};
        }

    int srow = tid >> 2;
    int scol = (tid & 3) * 8;
    const int frow = lane & 15;
    const int fk   = (lane >> 4) * 8;
    const int rbase = (lane >> 4) * 4;
    const int nkb = K >> 7;

    for (int kb = 0; kb < nkb; ++kb) {
#pragma unroll
        for (int ks = 0; ks < 4; ++ks) {
            int k0 = kb * 128 + ks * 32;
            __syncthreads();
#pragma unroll
            for (int hh = 0; hh < 2; ++hh) {
                int r = srow + hh * 64;
                *(int4*)(void*)(As + r * LDST + scol) =
                    *(const int4*)(const void*)(Aq + (size_t)(bm + r) * K + k0 + scol);
                *(int4*)(void*)(Bs + r * LDST + scol) =
                    *(const int4*)(const void*)(Bq + (size_t)(bn + r) * K + k0 + scol);
            }
            __syncthreads();
            s16x8 af[4], bfr[4];
#pragma unroll
            for (int m = 0; m < 4; ++m)
                af[m] = *(const s16x8*)(const void*)(As + (wr * 64 + m * 16 + frow) * LDST + fk);
#pragma unroll
            for (int n = 0; n < 4; ++n)
                bfr[n] = *(const s16x8*)(const void*)(Bs + (wc * 64 + n * 16 + frow) * LDST + fk);
#pragma unroll
            for (int m = 0; m < 4; ++m)
#pragma unroll
                for (int n = 0; n < 4; ++n)
                    accp[m][n] = __builtin_amdgcn_mfma_f32_16x16x32_bf16(af[m], bfr[n], accp[m][n], 0, 0, 0);
        }
#pragma unroll
        for (int m = 0; m < 4; ++m) {
            int rowb = bm + wr * 64 + m * 16 + rbase;
            float s0 = Sa[(size_t)(rowb + 0) * nkb + kb];
            float s1 = Sa[(size_t)(rowb + 1) * nkb + kb];
            float s2 = Sa[(size_t)(rowb + 2) * nkb + kb];
            float s3 = Sa[(size_t)(rowb + 3) * nkb + kb];
#pragma unroll
            for (int n = 0; n < 4; ++n) {
                acc[m][n][0] += s0 * accp[m][n][0];
                acc[m][n][1] += s1 * accp[m][n][1];
                acc[m][n][2] += s2 * accp[m][n][2];
                acc[m][n][3] += s3 * accp[m][n][3];
                accp[m][n] = (f32x4){0.f, 0.f, 0.f, 0.f};
            }
        }
    }

    int row0 = bm + wr * 64, col0 = bn + wc * 64;
    int cl = lane & 15;
#pragma unroll
    for (int n = 0; n < 4; ++n) {
        float sb = Sb[(col0 + n * 16) >> 7];
#pragma unroll
        for (int m = 0; m < 4; ++m)
#pragma unroll
            for (int r = 0; r < 4; ++r) {
                int row = row0 + m * 16 + rbase + r;
                int col = col0 + n * 16 + cl;
                float val = acc[m][n][r] * sb;
                if (OUTF32) {
                    Of[(size_t)row * N + col] = val;
                } else {
                    unsigned short hi = f2bf(val);
                    Oh[(size_t)row * N + col] = hi;
                    Ol[(size_t)row * N + col] = f2bf(val - bf2f(hi));
                }
            }
    }
}

// ---------- V transpose: [B,T,H*D] plane -> [B,H,D,T] plane (one plane per call) ----------
// 64x64 tiles, LDS with XOR swizzle (col ^= (row>>3)<<3): coalesced global R/W,
// LDS read 2-way (free).
__global__ __launch_bounds__(256) void vtrans_k(const unsigned short* __restrict__ in_p,
                                                unsigned short* __restrict__ out_p) {
    __shared__ unsigned short tile[64 * 72];
    int t0 = blockIdx.x * 64, d0 = blockIdx.y * 64;
    int b = blockIdx.z >> 4, h = blockIdx.z & 15;
    int tid = threadIdx.x;
    int r = tid >> 3, c8 = (tid & 7) * 8;     // r:0..31, c8:0..56
    const unsigned short* in = in_p + ((size_t)b * Tdim + t0) * Cdim + h * Dh + d0;
    unsigned short* out = out_p + (((size_t)b * Hn + h) * Dh + d0) * Tdim + t0;
#pragma unroll
    for (int rr = r; rr < 64; rr += 32) {
        int cs = c8 ^ ((rr >> 3) << 3);
        *(int4*)(void*)(tile + rr * 72 + cs) =
            *(const int4*)(const void*)(in + (size_t)rr * Cdim + c8);
    }
    __syncthreads();
#pragma unroll
    for (int dr = r; dr < 64; dr += 32) {
        s16x8 v;
#pragma unroll
        for (int j = 0; j < 8; ++j) {
            int row = c8 + j;                         // t-local
            int col = dr ^ ((row >> 3) << 3);         // swizzled d-local
            v[j] = (short)tile[row * 72 + col];
        }
        *(s16x8*)(void*)(out + (size_t)dr * Tdim + c8) = v;
    }
}

// ---------- flash attention: barrier-free, K/V direct from global (L2/L3-resident) ----------
#define QB 64
#define KB 32
#define PLD 40   // Ps row stride

__global__ __launch_bounds__(256) void attn_k(const unsigned short* __restrict__ Qh,
                                              const unsigned short* __restrict__ Ql,
                                              const unsigned short* __restrict__ Kh,
                                              const unsigned short* __restrict__ Kl,
                                              const unsigned short* __restrict__ Vth,
                                              const unsigned short* __restrict__ Vtl,
                                              unsigned short* __restrict__ ctxq,
                                              float* __restrict__ Sc) {
    __shared__ unsigned short Psh[4][16 * PLD], Psl[4][16 * PLD];

    int tid = threadIdx.x, lane = tid & 63, wid = tid >> 6;
    int qt = blockIdx.x, h = blockIdx.y, b = blockIdx.z;
    const size_t qkbase = (size_t)b * Tdim * Cdim + (size_t)h * Dh;  // row-major Q,K
    const size_t vbase  = ((size_t)b * Hn + h) * (size_t)Dh * Tdim;  // transposed V
    const unsigned short* Qhp = Qh + qkbase;
    const unsigned short* Qlp = Ql + qkbase;
    const unsigned short* Khp = Kh + qkbase;
    const unsigned short* Klp = Kl + qkbase;
    const unsigned short* Vhp = Vth + vbase;
    const unsigned short* Vlp = Vtl + vbase;

    int q0 = qt * QB;
    int qrow_lo = q0 + wid * 16;
    int cl = lane & 15;
    int fk = (lane >> 4) * 8;
    int rb4 = (lane >> 4) * 4;
    int myrow = qrow_lo + cl;

    s16x8 qfh[4], qfl[4];
#pragma unroll
    for (int c = 0; c < 4; ++c) {
        qfh[c] = *(const s16x8*)(const void*)(Qhp + (size_t)myrow * Cdim + c * 32 + fk);
        qfl[c] = *(const s16x8*)(const void*)(Qlp + (size_t)myrow * Cdim + c * 32 + fk);
    }

    f32x4 acc[8];
#pragma unroll
    for (int n = 0; n < 8; ++n) acc[n] = (f32x4){0.f, 0.f, 0.f, 0.f};
    float mrun[4], lrun[4];
#pragma unroll
    for (int r = 0; r < 4; ++r) { mrun[r] = -__builtin_inff(); lrun[r] = 0.f; }

    const float scale = 0.088388347648318447f;  // 1/sqrt(128)
    int ntw = (qrow_lo + 15) / KB + 1;          // causal per-wave tile count

    for (int t = 0; t < ntw; ++t) {
        int j0 = t * KB;
        // ---- QK^T: K fragments straight from global (16B/lane, 64B segments) ----
        f32x4 sf[2];
#pragma unroll
        for (int st = 0; st < 2; ++st) {
            const unsigned short* krow = Khp + (size_t)(j0 + st * 16 + cl) * Cdim + fk;
            const unsigned short* lrow = Klp + (size_t)(j0 + st * 16 + cl) * Cdim + fk;
            s16x8 kfh[4], kfl[4];
#pragma unroll
            for (int c = 0; c < 4; ++c) {
                kfh[c] = *(const s16x8*)(const void*)(krow + c * 32);
                kfl[c] = *(const s16x8*)(const void*)(lrow + c * 32);
            }
            f32x4 sa = (f32x4){0.f, 0.f, 0.f, 0.f};
#pragma unroll
            for (int c = 0; c < 4; ++c) {
                sa = __builtin_amdgcn_mfma_f32_16x16x32_bf16(qfh[c], kfh[c], sa, 0, 0, 0);
                sa = __builtin_amdgcn_mfma_f32_16x16x32_bf16(qfh[c], kfl[c], sa, 0, 0, 0);
                sa = __builtin_amdgcn_mfma_f32_16x16x32_bf16(qfl[c], kfh[c], sa, 0, 0, 0);
            }
            sf[st] = sa;
        }
        // ---- scale + causal mask ----
#pragma unroll
        for (int st = 0; st < 2; ++st) {
            int key = j0 + st * 16 + cl;
#pragma unroll
            for (int r = 0; r < 4; ++r) {
                int qr = qrow_lo + rb4 + r;
                float sv = sf[st][r] * scale;
                sf[st][r] = (key <= qr) ? sv : -__builtin_inff();
            }
        }
        // ---- online softmax (rows live in 16-lane groups) ----
        float p0[4], p1[4], corr[4];
#pragma unroll
        for (int r = 0; r < 4; ++r) {
            float tm = fmaxf(sf[0][r], sf[1][r]);
#pragma unroll
            for (int o = 8; o; o >>= 1) tm = fmaxf(tm, __shfl_xor(tm, o));
            float mn = fmaxf(mrun[r], tm);
            corr[r] = __expf(mrun[r] - mn);
            mrun[r] = mn;
            p0[r] = __expf(sf[0][r] - mn);
            p1[r] = __expf(sf[1][r] - mn);
            float rs = p0[r] + p1[r];
#pragma unroll
            for (int o = 8; o; o >>= 1) rs += __shfl_xor(rs, o);
            lrun[r] = lrun[r] * corr[r] + rs;
        }
#pragma unroll
        for (int n = 0; n < 8; ++n)
#pragma unroll
            for (int r = 0; r < 4; ++r) acc[n][r] *= corr[r];
        // ---- P: C-layout -> A-frag layout via per-wave LDS bounce ----
        unsigned short* psh = &Psh[wid][0];
        unsigned short* psl = &Psl[wid][0];
#pragma unroll
        for (int r = 0; r < 4; ++r) {
            unsigned short h0 = f2bf(p0[r]);
            unsigned short h1 = f2bf(p1[r]);
            psh[(rb4 + r) * PLD + cl]      = h0;
            psl[(rb4 + r) * PLD + cl]      = f2bf(p0[r] - bf2f(h0));
            psh[(rb4 + r) * PLD + 16 + cl] = h1;
            psl[(rb4 + r) * PLD + 16 + cl] = f2bf(p1[r] - bf2f(h1));
        }
        s16x8 pfh = *(const s16x8*)(const void*)(psh + cl * PLD + fk);
        s16x8 pfl = *(const s16x8*)(const void*)(psl + cl * PLD + fk);
        // ---- PV: V fragments straight from transposed global ----
#pragma unroll
        for (int half = 0; half < 2; ++half) {
            s16x8 vfh[4], vfl[4];
#pragma unroll
            for (int n2 = 0; n2 < 4; ++n2) {
                int n = half * 4 + n2;
                vfh[n2] = *(const s16x8*)(const void*)(Vhp + (size_t)(n * 16 + cl) * Tdim + j0 + fk);
                vfl[n2] = *(const s16x8*)(const void*)(Vlp + (size_t)(n * 16 + cl) * Tdim + j0 + fk);
            }
#pragma unroll
            for (int n2 = 0; n2 < 4; ++n2) {
                int n = half * 4 + n2;
                acc[n] = __builtin_amdgcn_mfma_f32_16x16x32_bf16(pfh, vfh[n2], acc[n], 0, 0, 0);
                acc[n] = __builtin_amdgcn_mfma_f32_16x16x32_bf16(pfh, vfl[n2], acc[n], 0, 0, 0);
                acc[n] = __builtin_amdgcn_mfma_f32_16x16x32_bf16(pfl, vfh[n2], acc[n], 0, 0, 0);
            }
        }
    }
    // ---- epilogue: normalize + fused e5m2 block quant (block == head's 128 cols) ----
    unsigned short* cq = ctxq + qkbase;
#pragma unroll
    for (int r = 0; r < 4; ++r) {
        int trow = qrow_lo + rb4 + r;
        float inv = 1.0f / lrun[r];
        float vals[8];
        float am = 0.f;
#pragma unroll
        for (int n = 0; n < 8; ++n) {
            vals[n] = acc[n][r] * inv;
            am = fmaxf(am, fabsf(vals[n]));
        }
#pragma unroll
        for (int o = 8; o; o >>= 1) am = fmaxf(am, __shfl_xor(am, o));
        float s = fmaxf(am / 57344.0f, 1e-12f);
#pragma unroll
        for (int n = 0; n < 8; ++n)
            cq[(size_t)trow * Cdim + n * 16 + cl] = f2bf(q8_e5m2(vals[n] / s));
        if (cl == 0) Sc[((size_t)b * Tdim + trow) * NKB + h] = s;
    }
}

// ---------- launch ----------
extern "C" void kernel_launch(void* const* d_in, const int* in_sizes, int n_in,
                              void* d_out, int out_size, void* d_ws, size_t ws_size,
                              hipStream_t stream) {
    const float* x  = (const float*)d_in[0];
    const float* wq = (const float*)d_in[2];
    const float* wk = (const float*)d_in[3];
    const float* wv = (const float*)d_in[4];
    const float* wo = (const float*)d_in[5];
    const float* sq = (const float*)d_in[6];
    const float* sk = (const float*)d_in[7];
    const float* sv = (const float*)d_in[8];
    const float* so = (const float*)d_in[9];

    const size_t MB = 1ull << 20;
    char* ws = (char*)d_ws;
    // lifetime-overlapped workspace map (peak 120.5 MB):
    unsigned short* xq  = (unsigned short*)(ws);                       // 0..16: xq -> vth
    unsigned short* vth = (unsigned short*)(ws);
    float*          Sx  = (float*)(ws + 16 * MB);                      // 16..16.25
    float*          Scx = (float*)(ws + (16 * MB + 256 * 1024));       // 16.25..16.5
    unsigned short* wdq = (unsigned short*)(ws + (16 * MB + 512 * 1024)); // 16.5..24.5
    unsigned short* qh  = (unsigned short*)(ws + (24 * MB + 512 * 1024));
    unsigned short* ql  = (unsigned short*)(ws + (40 * MB + 512 * 1024));
    unsigned short* kh  = (unsigned short*)(ws + (56 * MB + 512 * 1024));
    unsigned short* kl  = (unsigned short*)(ws + (72 * MB + 512 * 1024));
    unsigned short* vh  = (unsigned short*)(ws + (88 * MB + 512 * 1024));  // vh -> vtl
    unsigned short* vtl = (unsigned short*)(ws + (88 * MB + 512 * 1024));
    unsigned short* vl  = (unsigned short*)(ws + (104 * MB + 512 * 1024)); // vl -> cq
    unsigned short* cq  = (unsigned short*)(ws + (104 * MB + 512 * 1024));

    const int n128 = Bdim * Tdim * Cdim / 128;  // 65536
    const int wn = Cdim * Cdim;
    const int Mr = Bdim * Tdim;

    act_quant_q8_k<<<n128 / 4, 256, 0, stream>>>(x, xq, Sx, n128);

    dim3 gg(Cdim / 128, Mr / 128);
    w_quant_k<<<wn / 1024, 256, 0, stream>>>(wq, wdq, wn);
    gemm_k<0><<<gg, 256, 0, stream>>>(xq, Sx, wdq, sq, qh, ql, nullptr, Mr, Cdim, Cdim);
    w_quant_k<<<wn / 1024, 256, 0, stream>>>(wk, wdq, wn);
    gemm_k<0><<<gg, 256, 0, stream>>>(xq, Sx, wdq, sk, kh, kl, nullptr, Mr, Cdim, Cdim);
    w_quant_k<<<wn / 1024, 256, 0, stream>>>(wv, wdq, wn);
    gemm_k<0><<<gg, 256, 0, stream>>>(xq, Sx, wdq, sv, vh, vl, nullptr, Mr, Cdim, Cdim);

    // transpose V planes: vh -> vth (over dead xq), then vl -> vtl (over dead vh)
    dim3 tg(Tdim / 64, Dh / 64, Bdim * Hn);
    vtrans_k<<<tg, 256, 0, stream>>>(vh, vth);
    vtrans_k<<<tg, 256, 0, stream>>>(vl, vtl);

    dim3 ag(Tdim / QB, Hn, Bdim);
    attn_k<<<ag, 256, 0, stream>>>(qh, ql, kh, kl, vth, vtl, cq, Scx);  // cq over dead vl

    w_quant_k<<<wn / 1024, 256, 0, stream>>>(wo, wdq, wn);
    gemm_k<1><<<gg, 256, 0, stream>>>(cq, Scx, wdq, so, nullptr, nullptr, (float*)d_out, Mr, Cdim, Cdim);
}

// Round 4
// 769.609 us; speedup vs baseline: 1.5519x; 1.5519x over previous
//
#include <hip/hip_runtime.h>

#define Bdim 2
#define Tdim 2048
#define Cdim 2048
#define Hn 16
#define Dh 128
#define NKB 16   // Cdim/128 k-blocks per row

typedef float f32x4 __attribute__((ext_vector_type(4)));
typedef short s16x8 __attribute__((ext_vector_type(8)));

// ---------- numerics helpers ----------

// fp32 -> float8_e5m2 (RNE, subnormals, inf past 61440) -> fp32. Matches ml_dtypes.
__device__ __forceinline__ float q8_e5m2(float x) {
    unsigned int u = __float_as_uint(x);
    unsigned int sign = u & 0x80000000u;
    float ax = __uint_as_float(u & 0x7fffffffu);
    float r;
    if (ax < 6.103515625e-05f) {              // subnormal range: grid 2^-16
        r = rintf(ax * 65536.0f) * (1.0f / 65536.0f);
    } else if (ax >= 61440.0f) {
        r = __uint_as_float(0x7f800000u);
    } else {
        unsigned int m = __float_as_uint(ax);
        unsigned int rem  = m & 0x001FFFFFu;
        unsigned int keep = m & 0xFFE00000u;
        unsigned int lsb  = (m >> 21) & 1u;
        if (rem > 0x00100000u || (rem == 0x00100000u && lsb)) keep += 0x00200000u;
        r = __uint_as_float(keep);
    }
    return __uint_as_float(__float_as_uint(r) | sign);
}

__device__ __forceinline__ unsigned short f2bf(float f) {
    unsigned int u = __float_as_uint(f);
    u += 0x7fffu + ((u >> 16) & 1u);
    return (unsigned short)(u >> 16);
}
__device__ __forceinline__ float bf2f(unsigned short h) {
    return __uint_as_float((unsigned int)h << 16);
}

// ---------- act quant: per-128 block. out = bf16(q8(x/s)) [EXACT] + scale ----------
__global__ __launch_bounds__(256) void act_quant_q8_k(const float* __restrict__ in,
                                                      unsigned short* __restrict__ q,
                                                      float* __restrict__ S, int n128) {
    int wid = (int)((blockIdx.x * 256u + threadIdx.x) >> 6);
    int lane = threadIdx.x & 63;
    if (wid >= n128) return;
    const float* p = in + (size_t)wid * 128;
    float a = p[lane], b = p[lane + 64];
    float m = fmaxf(fabsf(a), fabsf(b));
#pragma unroll
    for (int o = 32; o; o >>= 1) m = fmaxf(m, __shfl_xor(m, o));
    float s = fmaxf(m / 57344.0f, 1e-12f);
    unsigned short* qp = q + (size_t)wid * 128;
    qp[lane]      = f2bf(q8_e5m2(a / s));
    qp[lane + 64] = f2bf(q8_e5m2(b / s));
    if (lane == 0) S[wid] = s;
}

// ---------- weight quant: out = bf16(q8(w)) [EXACT, scale in GEMM epilogue] ----------
__global__ __launch_bounds__(256) void w_quant_k(const float* __restrict__ w,
                                                 unsigned short* __restrict__ out, int n) {
    int i = (blockIdx.x * 256 + threadIdx.x) * 4;
    if (i >= n) return;
    float4 t = *(const float4*)(w + i);
    out[i + 0] = f2bf(q8_e5m2(t.x));
    out[i + 1] = f2bf(q8_e5m2(t.y));
    out[i + 2] = f2bf(q8_e5m2(t.z));
    out[i + 3] = f2bf(q8_e5m2(t.w));
}

// ---------- GEMM: C[M,N] = (Aq * Sa_blockwise) @ Bq^T * Sb_col ----------
#define LDST 40

template<int OUTF32>
__global__ __launch_bounds__(256) void gemm_k(const unsigned short* __restrict__ Aq,
                                              const float* __restrict__ Sa,
                                              const unsigned short* __restrict__ Bq,
                                              const float* __restrict__ Sb,
                                              unsigned short* __restrict__ Oh,
                                              unsigned short* __restrict__ Ol,
                                              float* __restrict__ Of,
                                              int M, int N, int K) {
    __shared__ unsigned short As[128 * LDST];
    __shared__ unsigned short Bs[128 * LDST];
    int tid = threadIdx.x;
    int lane = tid & 63, wid = tid >> 6;
    int wr = wid >> 1, wc = wid & 1;
    int bm = blockIdx.y * 128, bn = blockIdx.x * 128;

    f32x4 acc[4][4], accp[4][4];
#pragma unroll
    for (int i = 0; i < 4; ++i)
#pragma unroll
        for (int j = 0; j < 4; ++j) {
            acc[i][j] = (f32x4){0.f, 0.f, 0.f, 0.f};
            accp[i][j] = (f32x4){0.f, 0.f, 0.f, 0.f};
        }

    int srow = tid >> 2;
    int scol = (tid & 3) * 8;
    const int frow = lane & 15;
    const int fk   = (lane >> 4) * 8;
    const int rbase = (lane >> 4) * 4;
    const int nkb = K >> 7;

    for (int kb = 0; kb < nkb; ++kb) {
#pragma unroll
        for (int ks = 0; ks < 4; ++ks) {
            int k0 = kb * 128 + ks * 32;
            __syncthreads();
#pragma unroll
            for (int hh = 0; hh < 2; ++hh) {
                int r = srow + hh * 64;
                *(int4*)(void*)(As + r * LDST + scol) =
                    *(const int4*)(const void*)(Aq + (size_t)(bm + r) * K + k0 + scol);
                *(int4*)(void*)(Bs + r * LDST + scol) =
                    *(const int4*)(const void*)(Bq + (size_t)(bn + r) * K + k0 + scol);
            }
            __syncthreads();
            s16x8 af[4], bfr[4];
#pragma unroll
            for (int m = 0; m < 4; ++m)
                af[m] = *(const s16x8*)(const void*)(As + (wr * 64 + m * 16 + frow) * LDST + fk);
#pragma unroll
            for (int n = 0; n < 4; ++n)
                bfr[n] = *(const s16x8*)(const void*)(Bs + (wc * 64 + n * 16 + frow) * LDST + fk);
#pragma unroll
            for (int m = 0; m < 4; ++m)
#pragma unroll
                for (int n = 0; n < 4; ++n)
                    accp[m][n] = __builtin_amdgcn_mfma_f32_16x16x32_bf16(af[m], bfr[n], accp[m][n], 0, 0, 0);
        }
#pragma unroll
        for (int m = 0; m < 4; ++m) {
            int rowb = bm + wr * 64 + m * 16 + rbase;
            float s0 = Sa[(size_t)(rowb + 0) * nkb + kb];
            float s1 = Sa[(size_t)(rowb + 1) * nkb + kb];
            float s2 = Sa[(size_t)(rowb + 2) * nkb + kb];
            float s3 = Sa[(size_t)(rowb + 3) * nkb + kb];
#pragma unroll
            for (int n = 0; n < 4; ++n) {
                acc[m][n][0] += s0 * accp[m][n][0];
                acc[m][n][1] += s1 * accp[m][n][1];
                acc[m][n][2] += s2 * accp[m][n][2];
                acc[m][n][3] += s3 * accp[m][n][3];
                accp[m][n] = (f32x4){0.f, 0.f, 0.f, 0.f};
            }
        }
    }

    int row0 = bm + wr * 64, col0 = bn + wc * 64;
    int cl = lane & 15;
#pragma unroll
    for (int n = 0; n < 4; ++n) {
        float sb = Sb[(col0 + n * 16) >> 7];
#pragma unroll
        for (int m = 0; m < 4; ++m)
#pragma unroll
            for (int r = 0; r < 4; ++r) {
                int row = row0 + m * 16 + rbase + r;
                int col = col0 + n * 16 + cl;
                float val = acc[m][n][r] * sb;
                if (OUTF32) {
                    Of[(size_t)row * N + col] = val;
                } else {
                    unsigned short hi = f2bf(val);
                    Oh[(size_t)row * N + col] = hi;
                    Ol[(size_t)row * N + col] = f2bf(val - bf2f(hi));
                }
            }
    }
}

// ---------- V transpose: [B,T,H*D] plane -> [B,H,D,T] plane ----------
__global__ __launch_bounds__(256) void vtrans_k(const unsigned short* __restrict__ in_p,
                                                unsigned short* __restrict__ out_p) {
    __shared__ unsigned short tile[64 * 72];
    int t0 = blockIdx.x * 64, d0 = blockIdx.y * 64;
    int b = blockIdx.z >> 4, h = blockIdx.z & 15;
    int tid = threadIdx.x;
    int r = tid >> 3, c8 = (tid & 7) * 8;
    const unsigned short* in = in_p + ((size_t)b * Tdim + t0) * Cdim + h * Dh + d0;
    unsigned short* out = out_p + (((size_t)b * Hn + h) * Dh + d0) * Tdim + t0;
#pragma unroll
    for (int rr = r; rr < 64; rr += 32) {
        int cs = c8 ^ ((rr >> 3) << 3);
        *(int4*)(void*)(tile + rr * 72 + cs) =
            *(const int4*)(const void*)(in + (size_t)rr * Cdim + c8);
    }
    __syncthreads();
#pragma unroll
    for (int dr = r; dr < 64; dr += 32) {
        s16x8 v;
#pragma unroll
        for (int j = 0; j < 8; ++j) {
            int row = c8 + j;
            int col = dr ^ ((row >> 3) << 3);
            v[j] = (short)tile[row * 72 + col];
        }
        *(s16x8*)(void*)(out + (size_t)dr * Tdim + c8) = v;
    }
}

// ---------- flash attention: paired q-tiles (balance) + pipelined K/V loads ----------
#define QB 64
#define KB 32
#define PLD 40   // Ps row stride

__global__ __launch_bounds__(256, 2) void attn_k(const unsigned short* __restrict__ Qh,
                                                 const unsigned short* __restrict__ Ql,
                                                 const unsigned short* __restrict__ Kh,
                                                 const unsigned short* __restrict__ Kl,
                                                 const unsigned short* __restrict__ Vth,
                                                 const unsigned short* __restrict__ Vtl,
                                                 unsigned short* __restrict__ ctxq,
                                                 float* __restrict__ Sc) {
    __shared__ unsigned short Psh[4][16 * PLD], Psl[4][16 * PLD];

    int tid = threadIdx.x, lane = tid & 63, wid = tid >> 6;
    int pr = blockIdx.x, h = blockIdx.y, b = blockIdx.z;   // pr: pair index 0..15
    const size_t qkbase = (size_t)b * Tdim * Cdim + (size_t)h * Dh;  // row-major Q,K
    const size_t vbase  = ((size_t)b * Hn + h) * (size_t)Dh * Tdim;  // transposed V
    const unsigned short* Qhp = Qh + qkbase;
    const unsigned short* Qlp = Ql + qkbase;
    const unsigned short* Khp = Kh + qkbase;
    const unsigned short* Klp = Kl + qkbase;
    const unsigned short* Vhp = Vth + vbase;
    const unsigned short* Vlp = Vtl + vbase;

    int cl = lane & 15;
    int fk = (lane >> 4) * 8;
    int rb4 = (lane >> 4) * 4;
    const float scale = 0.088388347648318447f;  // 1/sqrt(128)

    for (int pass = 0; pass < 2; ++pass) {
        int qt = pass ? (31 - pr) : pr;
        int qrow_lo = qt * QB + wid * 16;
        int myrow = qrow_lo + cl;

        s16x8 qfh[4], qfl[4];
#pragma unroll
        for (int c = 0; c < 4; ++c) {
            qfh[c] = *(const s16x8*)(const void*)(Qhp + (size_t)myrow * Cdim + c * 32 + fk);
            qfl[c] = *(const s16x8*)(const void*)(Qlp + (size_t)myrow * Cdim + c * 32 + fk);
        }

        f32x4 acc[8];
#pragma unroll
        for (int n = 0; n < 8; ++n) acc[n] = (f32x4){0.f, 0.f, 0.f, 0.f};
        float mrun[4], lrun[4];
#pragma unroll
        for (int r = 0; r < 4; ++r) { mrun[r] = -__builtin_inff(); lrun[r] = 0.f; }

        int ntw = (qrow_lo + 15) / KB + 1;

        // preload K(0)
        s16x8 kfh[2][4], kfl[2][4];
#pragma unroll
        for (int st = 0; st < 2; ++st) {
            const unsigned short* krow = Khp + (size_t)(st * 16 + cl) * Cdim + fk;
            const unsigned short* lrow = Klp + (size_t)(st * 16 + cl) * Cdim + fk;
#pragma unroll
            for (int c = 0; c < 4; ++c) {
                kfh[st][c] = *(const s16x8*)(const void*)(krow + c * 32);
                kfl[st][c] = *(const s16x8*)(const void*)(lrow + c * 32);
            }
        }

        for (int t = 0; t < ntw; ++t) {
            int j0 = t * KB;
            // ---- issue V half0 (d-rows 0..63) early: window = QK + softmax ----
            s16x8 vfh0[4], vfl0[4];
#pragma unroll
            for (int n2 = 0; n2 < 4; ++n2) {
                vfh0[n2] = *(const s16x8*)(const void*)(Vhp + (size_t)(n2 * 16 + cl) * Tdim + j0 + fk);
                vfl0[n2] = *(const s16x8*)(const void*)(Vlp + (size_t)(n2 * 16 + cl) * Tdim + j0 + fk);
            }
            // ---- QK^T on prefetched K ----
            f32x4 sf[2];
#pragma unroll
            for (int st = 0; st < 2; ++st) {
                f32x4 sa = (f32x4){0.f, 0.f, 0.f, 0.f};
#pragma unroll
                for (int c = 0; c < 4; ++c) {
                    sa = __builtin_amdgcn_mfma_f32_16x16x32_bf16(qfh[c], kfh[st][c], sa, 0, 0, 0);
                    sa = __builtin_amdgcn_mfma_f32_16x16x32_bf16(qfh[c], kfl[st][c], sa, 0, 0, 0);
                    sa = __builtin_amdgcn_mfma_f32_16x16x32_bf16(qfl[c], kfh[st][c], sa, 0, 0, 0);
                }
                sf[st] = sa;
            }
            // ---- issue K(t+1): window = softmax + bounce + PV ----
            if (t + 1 < ntw) {
                int j0n = j0 + KB;
#pragma unroll
                for (int st = 0; st < 2; ++st) {
                    const unsigned short* krow = Khp + (size_t)(j0n + st * 16 + cl) * Cdim + fk;
                    const unsigned short* lrow = Klp + (size_t)(j0n + st * 16 + cl) * Cdim + fk;
#pragma unroll
                    for (int c = 0; c < 4; ++c) {
                        kfh[st][c] = *(const s16x8*)(const void*)(krow + c * 32);
                        kfl[st][c] = *(const s16x8*)(const void*)(lrow + c * 32);
                    }
                }
            }
            // ---- issue V half1 ----
            s16x8 vfh1[4], vfl1[4];
#pragma unroll
            for (int n2 = 0; n2 < 4; ++n2) {
                vfh1[n2] = *(const s16x8*)(const void*)(Vhp + (size_t)((n2 + 4) * 16 + cl) * Tdim + j0 + fk);
                vfl1[n2] = *(const s16x8*)(const void*)(Vlp + (size_t)((n2 + 4) * 16 + cl) * Tdim + j0 + fk);
            }
            // ---- scale + causal mask ----
#pragma unroll
            for (int st = 0; st < 2; ++st) {
                int key = j0 + st * 16 + cl;
#pragma unroll
                for (int r = 0; r < 4; ++r) {
                    int qr = qrow_lo + rb4 + r;
                    float sv = sf[st][r] * scale;
                    sf[st][r] = (key <= qr) ? sv : -__builtin_inff();
                }
            }
            // ---- online softmax ----
            float p0[4], p1[4], corr[4];
#pragma unroll
            for (int r = 0; r < 4; ++r) {
                float tm = fmaxf(sf[0][r], sf[1][r]);
#pragma unroll
                for (int o = 8; o; o >>= 1) tm = fmaxf(tm, __shfl_xor(tm, o));
                float mn = fmaxf(mrun[r], tm);
                corr[r] = __expf(mrun[r] - mn);
                mrun[r] = mn;
                p0[r] = __expf(sf[0][r] - mn);
                p1[r] = __expf(sf[1][r] - mn);
                float rs = p0[r] + p1[r];
#pragma unroll
                for (int o = 8; o; o >>= 1) rs += __shfl_xor(rs, o);
                lrun[r] = lrun[r] * corr[r] + rs;
            }
#pragma unroll
            for (int n = 0; n < 8; ++n)
#pragma unroll
                for (int r = 0; r < 4; ++r) acc[n][r] *= corr[r];
            // ---- P bounce through per-wave LDS ----
            unsigned short* psh = &Psh[wid][0];
            unsigned short* psl = &Psl[wid][0];
#pragma unroll
            for (int r = 0; r < 4; ++r) {
                unsigned short h0 = f2bf(p0[r]);
                unsigned short h1 = f2bf(p1[r]);
                psh[(rb4 + r) * PLD + cl]      = h0;
                psl[(rb4 + r) * PLD + cl]      = f2bf(p0[r] - bf2f(h0));
                psh[(rb4 + r) * PLD + 16 + cl] = h1;
                psl[(rb4 + r) * PLD + 16 + cl] = f2bf(p1[r] - bf2f(h1));
            }
            s16x8 pfh = *(const s16x8*)(const void*)(psh + cl * PLD + fk);
            s16x8 pfl = *(const s16x8*)(const void*)(psl + cl * PLD + fk);
            // ---- PV ----
#pragma unroll
            for (int n2 = 0; n2 < 4; ++n2) {
                acc[n2] = __builtin_amdgcn_mfma_f32_16x16x32_bf16(pfh, vfh0[n2], acc[n2], 0, 0, 0);
                acc[n2] = __builtin_amdgcn_mfma_f32_16x16x32_bf16(pfh, vfl0[n2], acc[n2], 0, 0, 0);
                acc[n2] = __builtin_amdgcn_mfma_f32_16x16x32_bf16(pfl, vfh0[n2], acc[n2], 0, 0, 0);
            }
#pragma unroll
            for (int n2 = 0; n2 < 4; ++n2) {
                acc[n2 + 4] = __builtin_amdgcn_mfma_f32_16x16x32_bf16(pfh, vfh1[n2], acc[n2 + 4], 0, 0, 0);
                acc[n2 + 4] = __builtin_amdgcn_mfma_f32_16x16x32_bf16(pfh, vfl1[n2], acc[n2 + 4], 0, 0, 0);
                acc[n2 + 4] = __builtin_amdgcn_mfma_f32_16x16x32_bf16(pfl, vfh1[n2], acc[n2 + 4], 0, 0, 0);
            }
        }
        // ---- epilogue: normalize + fused e5m2 block quant ----
        unsigned short* cq = ctxq + qkbase;
#pragma unroll
        for (int r = 0; r < 4; ++r) {
            int trow = qrow_lo + rb4 + r;
            float inv = 1.0f / lrun[r];
            float vals[8];
            float am = 0.f;
#pragma unroll
            for (int n = 0; n < 8; ++n) {
                vals[n] = acc[n][r] * inv;
                am = fmaxf(am, fabsf(vals[n]));
            }
#pragma unroll
            for (int o = 8; o; o >>= 1) am = fmaxf(am, __shfl_xor(am, o));
            float s = fmaxf(am / 57344.0f, 1e-12f);
#pragma unroll
            for (int n = 0; n < 8; ++n)
                cq[(size_t)trow * Cdim + n * 16 + cl] = f2bf(q8_e5m2(vals[n] / s));
            if (cl == 0) Sc[((size_t)b * Tdim + trow) * NKB + h] = s;
        }
    }
}

// ---------- launch ----------
extern "C" void kernel_launch(void* const* d_in, const int* in_sizes, int n_in,
                              void* d_out, int out_size, void* d_ws, size_t ws_size,
                              hipStream_t stream) {
    const float* x  = (const float*)d_in[0];
    const float* wq = (const float*)d_in[2];
    const float* wk = (const float*)d_in[3];
    const float* wv = (const float*)d_in[4];
    const float* wo = (const float*)d_in[5];
    const float* sq = (const float*)d_in[6];
    const float* sk = (const float*)d_in[7];
    const float* sv = (const float*)d_in[8];
    const float* so = (const float*)d_in[9];

    const size_t MB = 1ull << 20;
    char* ws = (char*)d_ws;
    unsigned short* xq  = (unsigned short*)(ws);                       // 0..16: xq -> vth
    unsigned short* vth = (unsigned short*)(ws);
    float*          Sx  = (float*)(ws + 16 * MB);
    float*          Scx = (float*)(ws + (16 * MB + 256 * 1024));
    unsigned short* wdq = (unsigned short*)(ws + (16 * MB + 512 * 1024));
    unsigned short* qh  = (unsigned short*)(ws + (24 * MB + 512 * 1024));
    unsigned short* ql  = (unsigned short*)(ws + (40 * MB + 512 * 1024));
    unsigned short* kh  = (unsigned short*)(ws + (56 * MB + 512 * 1024));
    unsigned short* kl  = (unsigned short*)(ws + (72 * MB + 512 * 1024));
    unsigned short* vh  = (unsigned short*)(ws + (88 * MB + 512 * 1024));  // vh -> vtl
    unsigned short* vtl = (unsigned short*)(ws + (88 * MB + 512 * 1024));
    unsigned short* vl  = (unsigned short*)(ws + (104 * MB + 512 * 1024)); // vl -> cq
    unsigned short* cq  = (unsigned short*)(ws + (104 * MB + 512 * 1024));

    const int n128 = Bdim * Tdim * Cdim / 128;  // 65536
    const int wn = Cdim * Cdim;
    const int Mr = Bdim * Tdim;

    act_quant_q8_k<<<n128 / 4, 256, 0, stream>>>(x, xq, Sx, n128);

    dim3 gg(Cdim / 128, Mr / 128);
    w_quant_k<<<wn / 1024, 256, 0, stream>>>(wq, wdq, wn);
    gemm_k<0><<<gg, 256, 0, stream>>>(xq, Sx, wdq, sq, qh, ql, nullptr, Mr, Cdim, Cdim);
    w_quant_k<<<wn / 1024, 256, 0, stream>>>(wk, wdq, wn);
    gemm_k<0><<<gg, 256, 0, stream>>>(xq, Sx, wdq, sk, kh, kl, nullptr, Mr, Cdim, Cdim);
    w_quant_k<<<wn / 1024, 256, 0, stream>>>(wv, wdq, wn);
    gemm_k<0><<<gg, 256, 0, stream>>>(xq, Sx, wdq, sv, vh, vl, nullptr, Mr, Cdim, Cdim);

    dim3 tg(Tdim / 64, Dh / 64, Bdim * Hn);
    vtrans_k<<<tg, 256, 0, stream>>>(vh, vth);
    vtrans_k<<<tg, 256, 0, stream>>>(vl, vtl);

    dim3 ag(16, Hn, Bdim);   // pair index, head, batch — 512 blocks, uniform work
    attn_k<<<ag, 256, 0, stream>>>(qh, ql, kh, kl, vth, vtl, cq, Scx);

    w_quant_k<<<wn / 1024, 256, 0, stream>>>(wo, wdq, wn);
    gemm_k<1><<<gg, 256, 0, stream>>>(cq, Scx, wdq, so, nullptr, nullptr, (float*)d_out, Mr, Cdim, Cdim);
}

// Round 5
// 492.634 us; speedup vs baseline: 2.4244x; 1.5622x over previous
//
#include <hip/hip_runtime.h>

#define Bdim 2
#define Tdim 2048
#define Cdim 2048
#define Hn 16
#define Dh 128
#define NKB 16   // Cdim/128 k-blocks per row

typedef float f32x4 __attribute__((ext_vector_type(4)));
typedef short s16x8 __attribute__((ext_vector_type(8)));

// async global->LDS, 16B per lane, linear dest (base + lane*16)
#define GL16(g, l) __builtin_amdgcn_global_load_lds( \
    (const __attribute__((address_space(1))) unsigned int*)(g), \
    (__attribute__((address_space(3))) unsigned int*)(l), 16, 0, 0)

// ---------- numerics helpers ----------

// fp32 -> float8_e5m2 (RNE, subnormals, inf past 61440) -> fp32. Matches ml_dtypes.
__device__ __forceinline__ float q8_e5m2(float x) {
    unsigned int u = __float_as_uint(x);
    unsigned int sign = u & 0x80000000u;
    float ax = __uint_as_float(u & 0x7fffffffu);
    float r;
    if (ax < 6.103515625e-05f) {              // subnormal range: grid 2^-16
        r = rintf(ax * 65536.0f) * (1.0f / 65536.0f);
    } else if (ax >= 61440.0f) {
        r = __uint_as_float(0x7f800000u);
    } else {
        unsigned int m = __float_as_uint(ax);
        unsigned int rem  = m & 0x001FFFFFu;
        unsigned int keep = m & 0xFFE00000u;
        unsigned int lsb  = (m >> 21) & 1u;
        if (rem > 0x00100000u || (rem == 0x00100000u && lsb)) keep += 0x00200000u;
        r = __uint_as_float(keep);
    }
    return __uint_as_float(__float_as_uint(r) | sign);
}

__device__ __forceinline__ unsigned short f2bf(float f) {
    unsigned int u = __float_as_uint(f);
    u += 0x7fffu + ((u >> 16) & 1u);
    return (unsigned short)(u >> 16);
}
__device__ __forceinline__ float bf2f(unsigned short h) {
    return __uint_as_float((unsigned int)h << 16);
}

// ---------- act quant: per-128 block. out = bf16(q8(x/s)) [EXACT] + scale ----------
__global__ __launch_bounds__(256) void act_quant_q8_k(const float* __restrict__ in,
                                                      unsigned short* __restrict__ q,
                                                      float* __restrict__ S, int n128) {
    int wid = (int)((blockIdx.x * 256u + threadIdx.x) >> 6);
    int lane = threadIdx.x & 63;
    if (wid >= n128) return;
    const float* p = in + (size_t)wid * 128;
    float a = p[lane], b = p[lane + 64];
    float m = fmaxf(fabsf(a), fabsf(b));
#pragma unroll
    for (int o = 32; o; o >>= 1) m = fmaxf(m, __shfl_xor(m, o));
    float s = fmaxf(m / 57344.0f, 1e-12f);
    unsigned short* qp = q + (size_t)wid * 128;
    qp[lane]      = f2bf(q8_e5m2(a / s));
    qp[lane + 64] = f2bf(q8_e5m2(b / s));
    if (lane == 0) S[wid] = s;
}

// ---------- weight quant: out = bf16(q8(w)) [EXACT, scale in GEMM epilogue] ----------
__global__ __launch_bounds__(256) void w_quant_k(const float* __restrict__ w,
                                                 unsigned short* __restrict__ out, int n) {
    int i = (blockIdx.x * 256 + threadIdx.x) * 4;
    if (i >= n) return;
    float4 t = *(const float4*)(w + i);
    out[i + 0] = f2bf(q8_e5m2(t.x));
    out[i + 1] = f2bf(q8_e5m2(t.y));
    out[i + 2] = f2bf(q8_e5m2(t.z));
    out[i + 3] = f2bf(q8_e5m2(t.w));
}

// ---------- GEMM: C[M,N] = (Aq * Sa_blockwise) @ Bq^T * Sb_col ----------
#define LDST 40

template<int OUTF32>
__global__ __launch_bounds__(256) void gemm_k(const unsigned short* __restrict__ Aq,
                                              const float* __restrict__ Sa,
                                              const unsigned short* __restrict__ Bq,
                                              const float* __restrict__ Sb,
                                              unsigned short* __restrict__ Oh,
                                              unsigned short* __restrict__ Ol,
                                              float* __restrict__ Of,
                                              int M, int N, int K) {
    __shared__ unsigned short As[128 * LDST];
    __shared__ unsigned short Bs[128 * LDST];
    int tid = threadIdx.x;
    int lane = tid & 63, wid = tid >> 6;
    int wr = wid >> 1, wc = wid & 1;
    int bm = blockIdx.y * 128, bn = blockIdx.x * 128;

    f32x4 acc[4][4], accp[4][4];
#pragma unroll
    for (int i = 0; i < 4; ++i)
#pragma unroll
        for (int j = 0; j < 4; ++j) {
            acc[i][j] = (f32x4){0.f, 0.f, 0.f, 0.f};
            accp[i][j] = (f32x4){0.f, 0.f, 0.f, 0.f};
        }

    int srow = tid >> 2;
    int scol = (tid & 3) * 8;
    const int frow = lane & 15;
    const int fk   = (lane >> 4) * 8;
    const int rbase = (lane >> 4) * 4;
    const int nkb = K >> 7;

    for (int kb = 0; kb < nkb; ++kb) {
#pragma unroll
        for (int ks = 0; ks < 4; ++ks) {
            int k0 = kb * 128 + ks * 32;
            __syncthreads();
#pragma unroll
            for (int hh = 0; hh < 2; ++hh) {
                int r = srow + hh * 64;
                *(int4*)(void*)(As + r * LDST + scol) =
                    *(const int4*)(const void*)(Aq + (size_t)(bm + r) * K + k0 + scol);
                *(int4*)(void*)(Bs + r * LDST + scol) =
                    *(const int4*)(const void*)(Bq + (size_t)(bn + r) * K + k0 + scol);
            }
            __syncthreads();
            s16x8 af[4], bfr[4];
#pragma unroll
            for (int m = 0; m < 4; ++m)
                af[m] = *(const s16x8*)(const void*)(As + (wr * 64 + m * 16 + frow) * LDST + fk);
#pragma unroll
            for (int n = 0; n < 4; ++n)
                bfr[n] = *(const s16x8*)(const void*)(Bs + (wc * 64 + n * 16 + frow) * LDST + fk);
#pragma unroll
            for (int m = 0; m < 4; ++m)
#pragma unroll
                for (int n = 0; n < 4; ++n)
                    accp[m][n] = __builtin_amdgcn_mfma_f32_16x16x32_bf16(af[m], bfr[n], accp[m][n], 0, 0, 0);
        }
#pragma unroll
        for (int m = 0; m < 4; ++m) {
            int rowb = bm + wr * 64 + m * 16 + rbase;
            float s0 = Sa[(size_t)(rowb + 0) * nkb + kb];
            float s1 = Sa[(size_t)(rowb + 1) * nkb + kb];
            float s2 = Sa[(size_t)(rowb + 2) * nkb + kb];
            float s3 = Sa[(size_t)(rowb + 3) * nkb + kb];
#pragma unroll
            for (int n = 0; n < 4; ++n) {
                acc[m][n][0] += s0 * accp[m][n][0];
                acc[m][n][1] += s1 * accp[m][n][1];
                acc[m][n][2] += s2 * accp[m][n][2];
                acc[m][n][3] += s3 * accp[m][n][3];
                accp[m][n] = (f32x4){0.f, 0.f, 0.f, 0.f};
            }
        }
    }

    int row0 = bm + wr * 64, col0 = bn + wc * 64;
    int cl = lane & 15;
#pragma unroll
    for (int n = 0; n < 4; ++n) {
        float sb = Sb[(col0 + n * 16) >> 7];
#pragma unroll
        for (int m = 0; m < 4; ++m)
#pragma unroll
            for (int r = 0; r < 4; ++r) {
                int row = row0 + m * 16 + rbase + r;
                int col = col0 + n * 16 + cl;
                float val = acc[m][n][r] * sb;
                if (OUTF32) {
                    Of[(size_t)row * N + col] = val;
                } else {
                    unsigned short hi = f2bf(val);
                    Oh[(size_t)row * N + col] = hi;
                    Ol[(size_t)row * N + col] = f2bf(val - bf2f(hi));
                }
            }
    }
}

// ---------- V transpose: [B,T,H*D] plane -> [B,H,D,T] plane ----------
__global__ __launch_bounds__(256) void vtrans_k(const unsigned short* __restrict__ in_p,
                                                unsigned short* __restrict__ out_p) {
    __shared__ unsigned short tile[64 * 72];
    int t0 = blockIdx.x * 64, d0 = blockIdx.y * 64;
    int b = blockIdx.z >> 4, h = blockIdx.z & 15;
    int tid = threadIdx.x;
    int r = tid >> 3, c8 = (tid & 7) * 8;
    const unsigned short* in = in_p + ((size_t)b * Tdim + t0) * Cdim + h * Dh + d0;
    unsigned short* out = out_p + (((size_t)b * Hn + h) * Dh + d0) * Tdim + t0;
#pragma unroll
    for (int rr = r; rr < 64; rr += 32) {
        int cs = c8 ^ ((rr >> 3) << 3);
        *(int4*)(void*)(tile + rr * 72 + cs) =
            *(const int4*)(const void*)(in + (size_t)rr * Cdim + c8);
    }
    __syncthreads();
#pragma unroll
    for (int dr = r; dr < 64; dr += 32) {
        s16x8 v;
#pragma unroll
        for (int j = 0; j < 8; ++j) {
            int row = c8 + j;
            int col = dr ^ ((row >> 3) << 3);
            v[j] = (short)tile[row * 72 + col];
        }
        *(s16x8*)(void*)(out + (size_t)dr * Tdim + c8) = v;
    }
}

// ---------- flash attention v3: LDS-staged K/V (gload_lds, dbuf), XCD affinity ----------
#define QB 64
#define KB 32
#define PLD 40   // Ps row stride

// stage one 32-key tile (K hi/lo from [t][d] layout, V hi/lo from [d][t] layout)
// into linear LDS with source pre-swizzle; each wave issues 8 gload_lds (1KB each).
__device__ __forceinline__ void stage_tile(const unsigned short* Khp, const unsigned short* Klp,
                                           const unsigned short* Vhp, const unsigned short* Vlp,
                                           unsigned short* Kbh, unsigned short* Kbl,
                                           unsigned short* Vbh, unsigned short* Vbl,
                                           int j0, int wid, int lane) {
#pragma unroll
    for (int i2 = 0; i2 < 2; ++i2) {
        int s = (wid * 2 + i2) * 64 + lane;
        // K planes: 32 rows x 16 chunks(16B); chunk swizzle ch' = ch ^ (r&7)
        int r = s >> 4, ch = (s & 15) ^ (r & 7);
        GL16(Khp + (size_t)(j0 + r) * Cdim + ch * 8, Kbh + s * 8);
        GL16(Klp + (size_t)(j0 + r) * Cdim + ch * 8, Kbl + s * 8);
        // V planes: 128 d-rows x 4 chunks(16B); chunk swizzle cv' = cv ^ ((d>>1)&3)
        int d = s >> 2, cv = (s & 3) ^ ((d >> 1) & 3);
        GL16(Vhp + (size_t)d * Tdim + j0 + cv * 8, Vbh + s * 8);
        GL16(Vlp + (size_t)d * Tdim + j0 + cv * 8, Vbl + s * 8);
    }
}

__global__ __launch_bounds__(256, 2) void attn_k(const unsigned short* __restrict__ Qh,
                                                 const unsigned short* __restrict__ Ql,
                                                 const unsigned short* __restrict__ Kh,
                                                 const unsigned short* __restrict__ Kl,
                                                 const unsigned short* __restrict__ Vth,
                                                 const unsigned short* __restrict__ Vtl,
                                                 unsigned short* __restrict__ ctxq,
                                                 float* __restrict__ Sc) {
    __shared__ unsigned short Kbh[2][4096], Kbl[2][4096];   // 8KB per buf per plane
    __shared__ unsigned short Vbh[2][4096], Vbl[2][4096];
    __shared__ unsigned short Psh[4][16 * PLD], Psl[4][16 * PLD];

    int tid = threadIdx.x, lane = tid & 63, wid = tid >> 6;
    // XCD-affinity decode: blocks with same (b,h) share blockIdx%8 -> same XCD
    int g = blockIdx.x;
    int xcd = g & 7, sl = g >> 3;
    int combo = xcd + 8 * (sl >> 4);     // 0..31
    int pr = sl & 15;                    // pair index
    int b = combo >> 4, h = combo & 15;

    const size_t qkbase = (size_t)b * Tdim * Cdim + (size_t)h * Dh;
    const size_t vbase  = ((size_t)b * Hn + h) * (size_t)Dh * Tdim;
    const unsigned short* Qhp = Qh + qkbase;
    const unsigned short* Qlp = Ql + qkbase;
    const unsigned short* Khp = Kh + qkbase;
    const unsigned short* Klp = Kl + qkbase;
    const unsigned short* Vhp = Vth + vbase;
    const unsigned short* Vlp = Vtl + vbase;

    int cl = lane & 15;
    int gq = lane >> 4;          // 16B chunk group 0..3
    int fk = gq * 8;
    int rb4 = gq * 4;
    const float scale = 0.088388347648318447f;  // 1/sqrt(128)

    for (int pass = 0; pass < 2; ++pass) {
        int qt = pass ? (31 - pr) : pr;
        int qrow_lo = qt * QB + wid * 16;
        int myrow = qrow_lo + cl;
        int qmax_w = qrow_lo + 15;

        s16x8 qfh[4], qfl[4];
#pragma unroll
        for (int c = 0; c < 4; ++c) {
            qfh[c] = *(const s16x8*)(const void*)(Qhp + (size_t)myrow * Cdim + c * 32 + fk);
            qfl[c] = *(const s16x8*)(const void*)(Qlp + (size_t)myrow * Cdim + c * 32 + fk);
        }

        f32x4 acc[8];
#pragma unroll
        for (int n = 0; n < 8; ++n) acc[n] = (f32x4){0.f, 0.f, 0.f, 0.f};
        float mrun[4], lrun[4];
#pragma unroll
        for (int r = 0; r < 4; ++r) { mrun[r] = -__builtin_inff(); lrun[r] = 0.f; }

        int ntile = 2 * qt + 2;   // block-level tile count (last q-row = qt*64+63)
        int cur = 0;

        stage_tile(Khp, Klp, Vhp, Vlp, Kbh[0], Kbl[0], Vbh[0], Vbl[0], 0, wid, lane);
        __syncthreads();

        for (int t = 0; t < ntile; ++t) {
            int j0 = t * KB;
            if (t + 1 < ntile)
                stage_tile(Khp, Klp, Vhp, Vlp, Kbh[cur ^ 1], Kbl[cur ^ 1],
                           Vbh[cur ^ 1], Vbl[cur ^ 1], j0 + KB, wid, lane);
            if (j0 <= qmax_w) {
                const unsigned short* kbh = Kbh[cur];
                const unsigned short* kbl = Kbl[cur];
                const unsigned short* vbh = Vbh[cur];
                const unsigned short* vbl = Vbl[cur];
                // ---- QK^T from LDS (swizzled b128 reads) ----
                f32x4 sf[2];
#pragma unroll
                for (int st = 0; st < 2; ++st) {
                    int rr = st * 16 + cl;
                    f32x4 sa = (f32x4){0.f, 0.f, 0.f, 0.f};
#pragma unroll
                    for (int c = 0; c < 4; ++c) {
                        int slot = rr * 16 + ((c * 4 + gq) ^ (rr & 7));
                        s16x8 kfh = *(const s16x8*)(const void*)(kbh + slot * 8);
                        s16x8 kfl = *(const s16x8*)(const void*)(kbl + slot * 8);
                        sa = __builtin_amdgcn_mfma_f32_16x16x32_bf16(qfh[c], kfh, sa, 0, 0, 0);
                        sa = __builtin_amdgcn_mfma_f32_16x16x32_bf16(qfh[c], kfl, sa, 0, 0, 0);
                        sa = __builtin_amdgcn_mfma_f32_16x16x32_bf16(qfl[c], kfh, sa, 0, 0, 0);
                    }
                    sf[st] = sa;
                }
                // ---- scale + causal mask ----
#pragma unroll
                for (int st = 0; st < 2; ++st) {
                    int key = j0 + st * 16 + cl;
#pragma unroll
                    for (int r = 0; r < 4; ++r) {
                        int qr = qrow_lo + rb4 + r;
                        float sv = sf[st][r] * scale;
                        sf[st][r] = (key <= qr) ? sv : -__builtin_inff();
                    }
                }
                // ---- online softmax ----
                float p0[4], p1[4], corr[4];
#pragma unroll
                for (int r = 0; r < 4; ++r) {
                    float tm = fmaxf(sf[0][r], sf[1][r]);
#pragma unroll
                    for (int o = 8; o; o >>= 1) tm = fmaxf(tm, __shfl_xor(tm, o));
                    float mn = fmaxf(mrun[r], tm);
                    corr[r] = __expf(mrun[r] - mn);
                    mrun[r] = mn;
                    p0[r] = __expf(sf[0][r] - mn);
                    p1[r] = __expf(sf[1][r] - mn);
                    float rs = p0[r] + p1[r];
#pragma unroll
                    for (int o = 8; o; o >>= 1) rs += __shfl_xor(rs, o);
                    lrun[r] = lrun[r] * corr[r] + rs;
                }
#pragma unroll
                for (int n = 0; n < 8; ++n)
#pragma unroll
                    for (int r = 0; r < 4; ++r) acc[n][r] *= corr[r];
                // ---- P bounce through per-wave LDS ----
                unsigned short* psh = &Psh[wid][0];
                unsigned short* psl = &Psl[wid][0];
#pragma unroll
                for (int r = 0; r < 4; ++r) {
                    unsigned short h0 = f2bf(p0[r]);
                    unsigned short h1 = f2bf(p1[r]);
                    psh[(rb4 + r) * PLD + cl]      = h0;
                    psl[(rb4 + r) * PLD + cl]      = f2bf(p0[r] - bf2f(h0));
                    psh[(rb4 + r) * PLD + 16 + cl] = h1;
                    psl[(rb4 + r) * PLD + 16 + cl] = f2bf(p1[r] - bf2f(h1));
                }
                s16x8 pfh = *(const s16x8*)(const void*)(psh + cl * PLD + fk);
                s16x8 pfl = *(const s16x8*)(const void*)(psl + cl * PLD + fk);
                // ---- PV from LDS ----
#pragma unroll
                for (int n = 0; n < 8; ++n) {
                    int d = n * 16 + cl;
                    int slot = d * 4 + (gq ^ ((d >> 1) & 3));
                    s16x8 vfh = *(const s16x8*)(const void*)(vbh + slot * 8);
                    s16x8 vfl = *(const s16x8*)(const void*)(vbl + slot * 8);
                    acc[n] = __builtin_amdgcn_mfma_f32_16x16x32_bf16(pfh, vfh, acc[n], 0, 0, 0);
                    acc[n] = __builtin_amdgcn_mfma_f32_16x16x32_bf16(pfh, vfl, acc[n], 0, 0, 0);
                    acc[n] = __builtin_amdgcn_mfma_f32_16x16x32_bf16(pfl, vfh, acc[n], 0, 0, 0);
                }
            }
            __syncthreads();   // drains gload_lds (vmcnt) + lgkm; next buf ready
            cur ^= 1;
        }
        // ---- epilogue: normalize + fused e5m2 block quant ----
        unsigned short* cq = ctxq + qkbase;
#pragma unroll
        for (int r = 0; r < 4; ++r) {
            int trow = qrow_lo + rb4 + r;
            float inv = 1.0f / lrun[r];
            float vals[8];
            float am = 0.f;
#pragma unroll
            for (int n = 0; n < 8; ++n) {
                vals[n] = acc[n][r] * inv;
                am = fmaxf(am, fabsf(vals[n]));
            }
#pragma unroll
            for (int o = 8; o; o >>= 1) am = fmaxf(am, __shfl_xor(am, o));
            float s = fmaxf(am / 57344.0f, 1e-12f);
#pragma unroll
            for (int n = 0; n < 8; ++n)
                cq[(size_t)trow * Cdim + n * 16 + cl] = f2bf(q8_e5m2(vals[n] / s));
            if (cl == 0) Sc[((size_t)b * Tdim + trow) * NKB + h] = s;
        }
    }
}

// ---------- launch ----------
extern "C" void kernel_launch(void* const* d_in, const int* in_sizes, int n_in,
                              void* d_out, int out_size, void* d_ws, size_t ws_size,
                              hipStream_t stream) {
    const float* x  = (const float*)d_in[0];
    const float* wq = (const float*)d_in[2];
    const float* wk = (const float*)d_in[3];
    const float* wv = (const float*)d_in[4];
    const float* wo = (const float*)d_in[5];
    const float* sq = (const float*)d_in[6];
    const float* sk = (const float*)d_in[7];
    const float* sv = (const float*)d_in[8];
    const float* so = (const float*)d_in[9];

    const size_t MB = 1ull << 20;
    char* ws = (char*)d_ws;
    unsigned short* xq  = (unsigned short*)(ws);                       // 0..16: xq -> vth
    unsigned short* vth = (unsigned short*)(ws);
    float*          Sx  = (float*)(ws + 16 * MB);
    float*          Scx = (float*)(ws + (16 * MB + 256 * 1024));
    unsigned short* wdq = (unsigned short*)(ws + (16 * MB + 512 * 1024));
    unsigned short* qh  = (unsigned short*)(ws + (24 * MB + 512 * 1024));
    unsigned short* ql  = (unsigned short*)(ws + (40 * MB + 512 * 1024));
    unsigned short* kh  = (unsigned short*)(ws + (56 * MB + 512 * 1024));
    unsigned short* kl  = (unsigned short*)(ws + (72 * MB + 512 * 1024));
    unsigned short* vh  = (unsigned short*)(ws + (88 * MB + 512 * 1024));  // vh -> vtl
    unsigned short* vtl = (unsigned short*)(ws + (88 * MB + 512 * 1024));
    unsigned short* vl  = (unsigned short*)(ws + (104 * MB + 512 * 1024)); // vl -> cq
    unsigned short* cq  = (unsigned short*)(ws + (104 * MB + 512 * 1024));

    const int n128 = Bdim * Tdim * Cdim / 128;  // 65536
    const int wn = Cdim * Cdim;
    const int Mr = Bdim * Tdim;

    act_quant_q8_k<<<n128 / 4, 256, 0, stream>>>(x, xq, Sx, n128);

    dim3 gg(Cdim / 128, Mr / 128);
    w_quant_k<<<wn / 1024, 256, 0, stream>>>(wq, wdq, wn);
    gemm_k<0><<<gg, 256, 0, stream>>>(xq, Sx, wdq, sq, qh, ql, nullptr, Mr, Cdim, Cdim);
    w_quant_k<<<wn / 1024, 256, 0, stream>>>(wk, wdq, wn);
    gemm_k<0><<<gg, 256, 0, stream>>>(xq, Sx, wdq, sk, kh, kl, nullptr, Mr, Cdim, Cdim);
    w_quant_k<<<wn / 1024, 256, 0, stream>>>(wv, wdq, wn);
    gemm_k<0><<<gg, 256, 0, stream>>>(xq, Sx, wdq, sv, vh, vl, nullptr, Mr, Cdim, Cdim);

    dim3 tg(Tdim / 64, Dh / 64, Bdim * Hn);
    vtrans_k<<<tg, 256, 0, stream>>>(vh, vth);
    vtrans_k<<<tg, 256, 0, stream>>>(vl, vtl);

    attn_k<<<512, 256, 0, stream>>>(qh, ql, kh, kl, vth, vtl, cq, Scx);

    w_quant_k<<<wn / 1024, 256, 0, stream>>>(wo, wdq, wn);
    gemm_k<1><<<gg, 256, 0, stream>>>(cq, Scx, wdq, so, nullptr, nullptr, (float*)d_out, Mr, Cdim, Cdim);
}